// Round 8
// baseline (548.575 us; speedup 1.0000x reference)
//
#include <hip/hip_runtime.h>
#include <math.h>

#define HW 4096
typedef short short8 __attribute__((ext_vector_type(8)));
typedef float floatx4 __attribute__((ext_vector_type(4)));

// ---- ws layout (bytes) ----
#define O_XBT   0ull            // [8][4096][512] bf16 x NHWC
#define O_PXB   33554432ull     // [8][4096][512] bf16 pooled x NHWC (reused later)
#define O_CATB  67108864ull     // [8][4096][512] bf16 cat branches NHWC
#define O_WPB   100663296ull    // [384][512] bf16
#define O_W4B   101056512ull    // [128][512] bf16
#define O_WCCB  101187584ull    // [512][512] bf16
#define O_WD2T  101711872ull    // [9][128][128] bf16 (t,o,c)
#define O_WD3T  102006784ull    // [25][128][128] bf16 (t,o,c)
#define O_WO2T  102825984ull    // [9][64][128] bf16 (t,o,c)
#define O_WO3T  102973440ull    // [25][64][128] bf16 (t,o,c)
// reuse of PXB region after b4 GEMM:
#define O_T2B   33554432ull     // [8][4096][128] bf16 b2i NHWC
#define O_T3B   41943040ull     // [8][4096][128] bf16 b3i NHWC
#define O_OFF2  50331648ull     // [8][18][4096] f32
#define O_OFF3  52690944ull     // [8][50][4096] f32

__device__ __forceinline__ unsigned short f2b(float f) {
    union { float f; unsigned u; } v; v.f = f;
    unsigned r = v.u + 0x7FFFu + ((v.u >> 16) & 1u);
    return (unsigned short)(r >> 16);
}
__device__ __forceinline__ float lou(unsigned u) {
    union { unsigned u; float f; } v; v.u = u << 16; return v.f;
}
__device__ __forceinline__ float hiu(unsigned u) {
    union { unsigned u; float f; } v; v.u = u & 0xFFFF0000u; return v.f;
}
__device__ __forceinline__ unsigned pk2(float lo, float hi) {
    return (unsigned)f2b(lo) | ((unsigned)f2b(hi) << 16);
}

// ------------------------------------------------------------- weight prep
__global__ __launch_bounds__(256) void k_prepw(
        const float* __restrict__ w1, const float* __restrict__ w21,
        const float* __restrict__ w31, const float* __restrict__ w4,
        const float* __restrict__ wcc, const float* __restrict__ wd2,
        const float* __restrict__ wd3, const float* __restrict__ wo2,
        const float* __restrict__ wo3, unsigned short* __restrict__ ws8) {
    unsigned i = blockIdx.x * 256 + threadIdx.x;
    unsigned short* wpb  = ws8 + (O_WPB  >> 1);
    unsigned short* w4b  = ws8 + (O_W4B  >> 1);
    unsigned short* wccb = ws8 + (O_WCCB >> 1);
    unsigned short* wd2t = ws8 + (O_WD2T >> 1);
    unsigned short* wd3t = ws8 + (O_WD3T >> 1);
    unsigned short* wo2t = ws8 + (O_WO2T >> 1);
    unsigned short* wo3t = ws8 + (O_WO3T >> 1);
    if (i < 196608) {
        int o = i >> 9;
        float v = (o < 128) ? w1[i] : (o < 256) ? w21[i - 65536] : w31[i - 131072];
        wpb[i] = f2b(v);
    } else if (i < 262144) {
        unsigned j = i - 196608; w4b[j] = f2b(w4[j]);
    } else if (i < 524288) {
        unsigned j = i - 262144; wccb[j] = f2b(wcc[j]);
    } else if (i < 671744) {
        unsigned j = i - 524288; int t = j >> 14, o = (j >> 7) & 127, c = j & 127;
        wd2t[j] = f2b(wd2[((o * 128 + c) * 9) + t]);
    } else if (i < 1081344) {
        unsigned j = i - 671744; int t = j >> 14, o = (j >> 7) & 127, c = j & 127;
        wd3t[j] = f2b(wd3[((o * 128 + c) * 25) + t]);
    } else if (i < 1155072) {
        // layout (t, o, c): j = (t*64 + o)*128 + c
        unsigned j = i - 1081344; int t = j >> 13, o = (j >> 7) & 63, c = j & 127;
        wo2t[j] = (o < 18) ? f2b(wo2[((o * 128 + c) * 9) + t]) : 0;
    } else if (i < 1359872) {
        unsigned j = i - 1155072; int t = j >> 13, o = (j >> 7) & 63, c = j & 127;
        wo3t[j] = (o < 50) ? f2b(wo3[((o * 128 + c) * 25) + t]) : 0;
    }
}

// ---------------------------------------- x NCHW f32 -> NHWC bf16 transpose
__global__ __launch_bounds__(256) void k_xpose(const float* __restrict__ X,
                                               unsigned short* __restrict__ xbT) {
    __shared__ unsigned short t[32][33];
    const int p0 = blockIdx.x * 32, c0 = blockIdx.y * 32, b = blockIdx.z;
    const int tid = threadIdx.x;
    #pragma unroll
    for (int s = 0; s < 4; ++s) {
        int cl = s * 8 + (tid >> 5), pl = tid & 31;
        t[cl][pl] = f2b(X[((size_t)b * 512 + c0 + cl) * HW + p0 + pl]);
    }
    __syncthreads();
    #pragma unroll
    for (int s = 0; s < 4; ++s) {
        int pl = s * 8 + (tid >> 5), cl = tid & 31;
        xbT[((size_t)b * HW + p0 + pl) * 512 + c0 + cl] = t[cl][pl];
    }
}

// ----------------------------------------------- 3x3 s1 maxpool on NHWC bf16
__global__ __launch_bounds__(256) void k_pool(const unsigned short* __restrict__ xbT,
                                              unsigned short* __restrict__ pxb) {
    unsigned gid = blockIdx.x * 256 + threadIdx.x;   // 8*4096*64
    int b = gid >> 18;
    unsigned rem = gid & 262143;
    int pos = rem >> 6;
    int cg = (rem & 63) * 8;
    int h = pos >> 6, w = pos & 63;
    const unsigned short* img = xbT + (size_t)b * HW * 512;
    float m[8] = {-INFINITY, -INFINITY, -INFINITY, -INFINITY,
                  -INFINITY, -INFINITY, -INFINITY, -INFINITY};
    #pragma unroll
    for (int dy = -1; dy <= 1; ++dy) {
        int hh = h + dy;
        if (hh < 0 || hh >= 64) continue;
        #pragma unroll
        for (int dx = -1; dx <= 1; ++dx) {
            int ww = w + dx;
            if (ww < 0 || ww >= 64) continue;
            uint4 v = *(const uint4*)(img + ((size_t)(hh * 64 + ww)) * 512 + cg);
            unsigned uu[4] = {v.x, v.y, v.z, v.w};
            #pragma unroll
            for (int e = 0; e < 4; ++e) {
                m[2 * e]     = fmaxf(m[2 * e],     lou(uu[e]));
                m[2 * e + 1] = fmaxf(m[2 * e + 1], hiu(uu[e]));
            }
        }
    }
    uint4 o;
    o.x = pk2(m[0], m[1]); o.y = pk2(m[2], m[3]);
    o.z = pk2(m[4], m[5]); o.w = pk2(m[6], m[7]);
    *(uint4*)(pxb + ((size_t)b * HW + pos) * 512 + cg) = o;
}

// ----------------------------- bf16 MFMA GEMM: C[128 x 128pos] = A[128x512]B
#define SA(r,c) SM[(r)*40 + (c)]
#define SB(r,c) SM[5120 + (r)*40 + (c)]
#define SC(r,c) SM[(r)*136 + (c)]
__global__ __launch_bounds__(256) void k_gemm(
        const unsigned short* __restrict__ A, const float* __restrict__ bias,
        const unsigned short* __restrict__ Bm,
        unsigned short* __restrict__ dst, int dStride, int dOff) {
    __shared__ unsigned short SM[17408];
    const int tid = threadIdx.x;
    const int n0 = blockIdx.x * 128;
    const int b = blockIdx.z;
    const int wave = tid >> 6, lane = tid & 63, quad = lane >> 4, lr = lane & 15;
    const int m0w = (wave & 1) * 64, n0w = (wave >> 1) * 64;
    const int srow = tid >> 1, skh = (tid & 1) * 16;
    floatx4 acc[4][4] = {};

    for (int k0 = 0; k0 < 512; k0 += 32) {
        const unsigned short* ga = A + (size_t)srow * 512 + k0 + skh;
        uint4 a0 = *(const uint4*)(ga);
        uint4 a1 = *(const uint4*)(ga + 8);
        const unsigned short* gb = Bm + ((size_t)b * HW + n0 + srow) * 512 + k0 + skh;
        uint4 b0 = *(const uint4*)(gb);
        uint4 b1 = *(const uint4*)(gb + 8);
        __syncthreads();
        *(uint4*)&SA(srow, skh) = a0;
        *(uint4*)&SA(srow, skh + 8) = a1;
        *(uint4*)&SB(srow, skh) = b0;
        *(uint4*)&SB(srow, skh + 8) = b1;
        __syncthreads();
        short8 af[4], bf[4];
        #pragma unroll
        for (int i = 0; i < 4; ++i) af[i] = *(short8*)&SA(m0w + i * 16 + lr, quad * 8);
        #pragma unroll
        for (int j = 0; j < 4; ++j) bf[j] = *(short8*)&SB(n0w + j * 16 + lr, quad * 8);
        #pragma unroll
        for (int i = 0; i < 4; ++i)
            #pragma unroll
            for (int j = 0; j < 4; ++j)
                acc[i][j] = __builtin_amdgcn_mfma_f32_16x16x32_bf16(af[i], bf[j], acc[i][j], 0, 0, 0);
    }
    __syncthreads();
    #pragma unroll
    for (int i = 0; i < 4; ++i) {
        float4 bs = *(const float4*)&bias[m0w + i * 16 + quad * 4];
        #pragma unroll
        for (int j = 0; j < 4; ++j) {
            floatx4 v = acc[i][j];
            int pos = n0w + j * 16 + lr;
            int ch = m0w + i * 16 + quad * 4;
            uint2 st;
            st.x = pk2(v[0] + bs.x, v[1] + bs.y);
            st.y = pk2(v[2] + bs.z, v[3] + bs.w);
            *(uint2*)&SC(pos, ch) = st;
        }
    }
    __syncthreads();
    #pragma unroll
    for (int r = 0; r < 8; ++r) {
        int pos = (tid >> 4) + r * 16;
        *(uint4*)&dst[((size_t)b * HW + n0 + pos) * dStride + dOff + (tid & 15) * 8] =
            *(uint4*)&SC(pos, (tid & 15) * 8);
    }
}

// ---------------- offset convs v2: slab-staged, barrier-free tap loop
// block = 128 positions (2 h-rows) x 64 M (padded), 512 threads.
template<int KS, int OCH>
__global__ __launch_bounds__(512) void k_offconv2(
        const unsigned short* __restrict__ img,   // [B][4096][128] bf16
        const unsigned short* __restrict__ woT,   // [TT][64][128] bf16 (t,o,c)
        const float* __restrict__ bias, float* __restrict__ Out) {
    constexpr int PAD = KS / 2;
    constexpr int TT = KS * KS;
    constexpr int SR = 2 + 2 * PAD;
    constexpr int SC2 = 64 + 2 * PAD;
    constexpr int NE = SR * SC2;              // slab entries
    __shared__ unsigned short slab[NE * 36];  // [entry][36] (32 ch + pad)
    __shared__ float ctile[64 * 132];
    const int tid = threadIdx.x;
    const int p0 = blockIdx.x * 128, hrow0 = blockIdx.x * 2, b = blockIdx.z;
    const int wave = tid >> 6, lane = tid & 63, quad = lane >> 4, lr = lane & 15;
    const int wm = wave & 1, wn = wave >> 1;   // 2 x 4 wave grid: 32o x 32pos
    const unsigned short* ib = img + (size_t)b * HW * 128;
    floatx4 acc[2][2] = {};

    for (int c0 = 0; c0 < 128; c0 += 32) {
        __syncthreads();
        if (tid < NE) {
            int s = tid / SC2, cl = tid % SC2;
            int r = hrow0 - PAD + s, cc = cl - PAD;
            uint4 v0 = {}, v1 = {}, v2 = {}, v3 = {};
            if ((unsigned)r < 64u && (unsigned)cc < 64u) {
                const uint4* g = (const uint4*)(ib + ((size_t)(r * 64 + cc)) * 128 + c0);
                v0 = g[0]; v1 = g[1]; v2 = g[2]; v3 = g[3];
            }
            uint2* d2 = (uint2*)&slab[tid * 36];
            d2[0] = make_uint2(v0.x, v0.y); d2[1] = make_uint2(v0.z, v0.w);
            d2[2] = make_uint2(v1.x, v1.y); d2[3] = make_uint2(v1.z, v1.w);
            d2[4] = make_uint2(v2.x, v2.y); d2[5] = make_uint2(v2.z, v2.w);
            d2[6] = make_uint2(v3.x, v3.y); d2[7] = make_uint2(v3.z, v3.w);
        }
        __syncthreads();
        #pragma unroll
        for (int t = 0; t < TT; ++t) {
            const int ky = t / KS, kx = t % KS;
            short8 af[2], bf[2];
            #pragma unroll
            for (int i = 0; i < 2; ++i)
                af[i] = *(const short8*)&woT[((size_t)t * 64 + wm * 32 + i * 16 + lr) * 128
                                             + c0 + quad * 8];
            #pragma unroll
            for (int j = 0; j < 2; ++j) {
                int p = wn * 32 + j * 16 + lr;
                int e = ((p >> 6) + ky) * SC2 + (p & 63) + kx;
                union { uint2 u[2]; short8 s; } bb;
                const uint2* sp = (const uint2*)&slab[e * 36 + quad * 8];
                bb.u[0] = sp[0]; bb.u[1] = sp[1];
                bf[j] = bb.s;
            }
            #pragma unroll
            for (int i = 0; i < 2; ++i)
                #pragma unroll
                for (int j = 0; j < 2; ++j)
                    acc[i][j] = __builtin_amdgcn_mfma_f32_16x16x32_bf16(af[i], bf[j], acc[i][j], 0, 0, 0);
        }
    }
    __syncthreads();
    #pragma unroll
    for (int i = 0; i < 2; ++i)
        #pragma unroll
        for (int j = 0; j < 2; ++j) {
            floatx4 v = acc[i][j];
            int p = wn * 32 + j * 16 + lr;
            int o = wm * 32 + i * 16 + quad * 4;
            #pragma unroll
            for (int rg = 0; rg < 4; ++rg)
                ctile[(o + rg) * 132 + p] = v[rg];
        }
    __syncthreads();
    {
        int o = tid >> 3, seg = tid & 7;
        if (o < OCH) {
            float bs = bias[o];
            const float* src = &ctile[o * 132 + seg * 16];
            float* dst = &Out[((size_t)b * OCH + o) * HW + p0 + seg * 16];
            #pragma unroll
            for (int q = 0; q < 4; ++q) {
                float4 v = *(const float4*)(src + q * 4);
                v.x += bs; v.y += bs; v.z += bs; v.w += bs;
                *(float4*)(dst + q * 4) = v;
            }
        }
    }
}

// ------------- deformable conv v11: GROUPED barriers (GS=KS taps per barrier)
// block = 256 threads (4 waves), tile = 128 o x 32 pos, grid = (128,1,8).
// Per group: {GS x (blend + LDS-write + next-gather, straight-line, NO
// barrier)} | barrier | prefetch next group's first gather | setprio(1) |
// {GS x (weights->regs + 16 MFMA)} | setprio(0) | barrier.
// Barriers 25->10 (KS5); gathers pipeline in straight-line code; next-group
// gather latency hidden under the whole MFMA burst. A/B corner-reg rotation
// breaks WAR. XCD-pinned batch (x&7) kept (FETCH 49.5->10.6MB proven).
// NOTE: pasted identifiers parenthesized — (cn##S##3).x — because 3.x lexes
// as one pp-number and the paste otherwise forms an invalid token.
#define DCG(S, T, DY, DX) do {                                                 \
    float fy = (float)(h + (T) / KS - PAD) + (DY);                             \
    float fx = (float)(w + (T) % KS - PAD) + (DX);                             \
    float y0f = floorf(fy), x0f = floorf(fx);                                  \
    float wyv = fy - y0f, wxv = fx - x0f;                                      \
    int y0 = (int)y0f, x0 = (int)x0f;                                          \
    w00 = (1.f - wyv) * (1.f - wxv); w01 = (1.f - wyv) * wxv;                  \
    w10 = wyv * (1.f - wxv);         w11 = wyv * wxv;                          \
    bool yv0 = (unsigned)y0 < 64u, yv1 = (unsigned)(y0 + 1) < 64u;             \
    bool xv0 = (unsigned)x0 < 64u, xv1 = (unsigned)(x0 + 1) < 64u;             \
    long bidx = (long)(y0 * 64 + x0) * 128 + cseg;                             \
    cn##S##0 = z4; cn##S##1 = z4; cn##S##2 = z4; cn##S##3 = z4;                \
    cn##S##4 = z4; cn##S##5 = z4; cn##S##6 = z4; cn##S##7 = z4;                \
    if (yv0 && xv0) { const uint4* p_ = (const uint4*)(ib + bidx);             \
        cn##S##0 = p_[0]; cn##S##1 = p_[1]; }                                  \
    if (yv0 && xv1) { const uint4* p_ = (const uint4*)(ib + bidx + 128);       \
        cn##S##2 = p_[0]; cn##S##3 = p_[1]; }                                  \
    if (yv1 && xv0) { const uint4* p_ = (const uint4*)(ib + bidx + 8192);      \
        cn##S##4 = p_[0]; cn##S##5 = p_[1]; }                                  \
    if (yv1 && xv1) { const uint4* p_ = (const uint4*)(ib + bidx + 8320);      \
        cn##S##6 = p_[0]; cn##S##7 = p_[1]; }                                  \
} while (0)

// blend with v_cvt_pk_bf16_f32 (RNE, bit-identical to f2b emulation)
#define DCB(S, O0, O1) do {                                                    \
    unsigned a_[8] = {(cn##S##0).x, (cn##S##0).y, (cn##S##0).z, (cn##S##0).w,  \
                      (cn##S##1).x, (cn##S##1).y, (cn##S##1).z, (cn##S##1).w}; \
    unsigned b_[8] = {(cn##S##2).x, (cn##S##2).y, (cn##S##2).z, (cn##S##2).w,  \
                      (cn##S##3).x, (cn##S##3).y, (cn##S##3).z, (cn##S##3).w}; \
    unsigned c_[8] = {(cn##S##4).x, (cn##S##4).y, (cn##S##4).z, (cn##S##4).w,  \
                      (cn##S##5).x, (cn##S##5).y, (cn##S##5).z, (cn##S##5).w}; \
    unsigned d_[8] = {(cn##S##6).x, (cn##S##6).y, (cn##S##6).z, (cn##S##6).w,  \
                      (cn##S##7).x, (cn##S##7).y, (cn##S##7).z, (cn##S##7).w}; \
    unsigned r_[8];                                                            \
    _Pragma("unroll")                                                          \
    for (int e_ = 0; e_ < 8; ++e_) {                                           \
        float lo_ = w00 * lou(a_[e_]) + w01 * lou(b_[e_])                      \
                  + w10 * lou(c_[e_]) + w11 * lou(d_[e_]);                     \
        float hi_ = w00 * hiu(a_[e_]) + w01 * hiu(b_[e_])                      \
                  + w10 * hiu(c_[e_]) + w11 * hiu(d_[e_]);                     \
        asm("v_cvt_pk_bf16_f32 %0, %1, %2"                                     \
            : "=v"(r_[e_]) : "v"(lo_), "v"(hi_));                              \
    }                                                                          \
    O0.x = r_[0]; O0.y = r_[1]; O0.z = r_[2]; O0.w = r_[3];                    \
    O1.x = r_[4]; O1.y = r_[5]; O1.z = r_[6]; O1.w = r_[7];                    \
} while (0)

template<int KS>
__global__ __launch_bounds__(256, 3) void k_deform11(
        const unsigned short* __restrict__ img,   // [B][4096][128] bf16
        const float* __restrict__ Off,            // [B][2TT][4096] f32
        const unsigned short* __restrict__ wdT,   // [TT][128][128] bf16 (t,o,c)
        const float* __restrict__ bias,
        unsigned short* __restrict__ catb, int dOff) {
    constexpr int PAD = KS / 2;
    constexpr int TT = KS * KS;
    constexpr int GS = KS;                     // taps per barrier group
    constexpr int NG = KS;                     // number of groups
    __shared__ unsigned short sS[GS][32][136]; // samples [tap-in-grp][pos][c]
    const int tid = threadIdx.x;
    // XCD-pinned remap: all blocks of batch b land on XCD b (L%8 model)
    const int b = blockIdx.x & 7;
    const int tile = (blockIdx.x >> 3) + 16 * blockIdx.z;  // 0..127
    const int p0 = tile * 32;
    const int wave = tid >> 6, lane = tid & 63, quad = lane >> 4, lr = lane & 15;
    const int m0w = wave * 32;                 // 4 m-waves x 32 o share 32 pos
    const int pos = tid >> 3;                  // 0..31
    const int cseg = (tid & 7) * 16;           // 16-ch segment
    const int pglob = p0 + pos;
    const int h = pglob >> 6, w = pglob & 63;
    const unsigned short* ib = img + (size_t)b * HW * 128;
    const float* offb = Off + (size_t)b * 2 * TT * HW;
    const uint4 z4 = make_uint4(0u, 0u, 0u, 0u);

    floatx4 acc00 = {}, acc01 = {}, acc10 = {}, acc11 = {};
    uint4 cnA0, cnA1, cnA2, cnA3, cnA4, cnA5, cnA6, cnA7;
    uint4 cnB0, cnB1, cnB2, cnB3, cnB4, cnB5, cnB6, cnB7;
    float w00, w01, w10, w11;
    float noy, nox;

    // prologue: gather tap 0 -> A; offsets for tap 1 -> (noy,nox)
    {
        float dy0 = offb[pglob];
        float dx0 = offb[HW + pglob];
        DCG(A, 0, dy0, dx0);
    }
    noy = offb[2 * HW + pglob];
    nox = offb[3 * HW + pglob];

    for (int g = 0; g < NG; ++g) {
        const int t0 = g * GS;
        // ---- write phase: GS taps, straight-line, no barriers ----
        #pragma unroll
        for (int tt = 0; tt < GS; ++tt) {
            uint4 ov0, ov1;
            if ((tt & 1) == 0) { DCB(A, ov0, ov1); } else { DCB(B, ov0, ov1); }
            *(uint4*)&sS[tt][pos][cseg] = ov0;
            *(uint4*)&sS[tt][pos][cseg + 8] = ov1;
            if (tt < GS - 1) {
                const int tn = t0 + tt + 1;
                if ((tt & 1) == 0) { DCG(B, tn, noy, nox); }
                else               { DCG(A, tn, noy, nox); }
                if (tn + 1 < TT) {
                    noy = offb[(size_t)(2 * tn + 2) * HW + pglob];
                    nox = offb[(size_t)(2 * tn + 3) * HW + pglob];
                }
            }
        }
        __syncthreads();
        // ---- prefetch next group's first tap into A (hidden under MFMAs) ----
        if (g + 1 < NG) {
            const int tn = t0 + GS;
            DCG(A, tn, noy, nox);
            if (tn + 1 < TT) {
                noy = offb[(size_t)(2 * tn + 2) * HW + pglob];
                nox = offb[(size_t)(2 * tn + 3) * HW + pglob];
            }
        }
        // ---- MFMA burst: GS taps ----
        __builtin_amdgcn_s_setprio(1);
        #pragma unroll
        for (int tt = 0; tt < GS; ++tt) {
            const int t = t0 + tt;
            const unsigned short* wb = wdT + (size_t)t * 16384
                                       + (size_t)(m0w + lr) * 128 + quad * 8;
            short8 wr0 = *(const short8*)(wb);
            short8 wr1 = *(const short8*)(wb + 2048);    // row +16
            short8 wr2 = *(const short8*)(wb + 32);      // ks=1
            short8 wr3 = *(const short8*)(wb + 2080);
            short8 wr4 = *(const short8*)(wb + 64);      // ks=2
            short8 wr5 = *(const short8*)(wb + 2112);
            short8 wr6 = *(const short8*)(wb + 96);      // ks=3
            short8 wr7 = *(const short8*)(wb + 2144);
            #pragma unroll
            for (int ks = 0; ks < 4; ++ks) {
                short8 bf0 = *(short8*)&sS[tt][lr][ks * 32 + quad * 8];
                short8 bf1 = *(short8*)&sS[tt][16 + lr][ks * 32 + quad * 8];
                short8 a0 = (ks == 0) ? wr0 : (ks == 1) ? wr2 : (ks == 2) ? wr4 : wr6;
                short8 a1 = (ks == 0) ? wr1 : (ks == 1) ? wr3 : (ks == 2) ? wr5 : wr7;
                acc00 = __builtin_amdgcn_mfma_f32_16x16x32_bf16(a0, bf0, acc00, 0, 0, 0);
                acc01 = __builtin_amdgcn_mfma_f32_16x16x32_bf16(a0, bf1, acc01, 0, 0, 0);
                acc10 = __builtin_amdgcn_mfma_f32_16x16x32_bf16(a1, bf0, acc10, 0, 0, 0);
                acc11 = __builtin_amdgcn_mfma_f32_16x16x32_bf16(a1, bf1, acc11, 0, 0, 0);
            }
        }
        __builtin_amdgcn_s_setprio(0);
        __syncthreads();
    }
    // epilogue: bias + bf16 pack via sS[0], coalesced store to catb
    {
        float4 bs = *(const float4*)&bias[m0w + quad * 4];
        float4 bs2 = *(const float4*)&bias[m0w + 16 + quad * 4];
        floatx4 v;
        uint2 st;
        int ch0 = m0w + quad * 4, ch1 = m0w + 16 + quad * 4;
        v = acc00;
        st.x = pk2(v[0] + bs.x, v[1] + bs.y);
        st.y = pk2(v[2] + bs.z, v[3] + bs.w);
        *(uint2*)&sS[0][lr][ch0] = st;
        v = acc01;
        st.x = pk2(v[0] + bs.x, v[1] + bs.y);
        st.y = pk2(v[2] + bs.z, v[3] + bs.w);
        *(uint2*)&sS[0][16 + lr][ch0] = st;
        v = acc10;
        st.x = pk2(v[0] + bs2.x, v[1] + bs2.y);
        st.y = pk2(v[2] + bs2.z, v[3] + bs2.w);
        *(uint2*)&sS[0][lr][ch1] = st;
        v = acc11;
        st.x = pk2(v[0] + bs2.x, v[1] + bs2.y);
        st.y = pk2(v[2] + bs2.z, v[3] + bs2.w);
        *(uint2*)&sS[0][16 + lr][ch1] = st;
    }
    __syncthreads();
    #pragma unroll
    for (int r = 0; r < 2; ++r) {
        int idx = r * 256 + tid;
        int p = idx >> 4, sg = (idx & 15) * 8;
        *(uint4*)&catb[((size_t)b * HW + p0 + p) * 512 + dOff + sg] =
            *(uint4*)&sS[0][p][sg];
    }
}

// ------------------- final: sigmoid(Wcc @ (catb*xbT)) + x, fp32 NCHW output
__global__ __launch_bounds__(256) void k_gemm_final(
        const unsigned short* __restrict__ A, const float* __restrict__ bias,
        const unsigned short* __restrict__ catb, const unsigned short* __restrict__ xbT,
        const float* __restrict__ X, float* __restrict__ OutF) {
    __shared__ unsigned short sA[128][40];
    __shared__ unsigned short sB[128][40];
    const int tid = threadIdx.x;
    const int n0 = blockIdx.x * 128;
    const int o0 = blockIdx.y * 128;
    const int b = blockIdx.z;
    const int wave = tid >> 6, lane = tid & 63, quad = lane >> 4, lr = lane & 15;
    const int m0w = (wave & 1) * 64, n0w = (wave >> 1) * 64;
    const int srow = tid >> 1, skh = (tid & 1) * 16;
    floatx4 acc[4][4] = {};

    for (int k0 = 0; k0 < 512; k0 += 32) {
        const unsigned short* ga = A + (size_t)(o0 + srow) * 512 + k0 + skh;
        uint4 a0 = *(const uint4*)(ga);
        uint4 a1 = *(const uint4*)(ga + 8);
        size_t bi = ((size_t)b * HW + n0 + srow) * 512 + k0 + skh;
        uint4 c0 = *(const uint4*)(catb + bi);
        uint4 c1 = *(const uint4*)(catb + bi + 8);
        uint4 x0 = *(const uint4*)(xbT + bi);
        uint4 x1 = *(const uint4*)(xbT + bi + 8);
        unsigned cu[8] = {c0.x, c0.y, c0.z, c0.w, c1.x, c1.y, c1.z, c1.w};
        unsigned xu[8] = {x0.x, x0.y, x0.z, x0.w, x1.x, x1.y, x1.z, x1.w};
        unsigned mu[8];
        #pragma unroll
        for (int e = 0; e < 8; ++e)
            mu[e] = pk2(lou(cu[e]) * lou(xu[e]), hiu(cu[e]) * hiu(xu[e]));
        __syncthreads();
        *(uint4*)&sA[srow][skh] = a0;
        *(uint4*)&sA[srow][skh + 8] = a1;
        uint4 m0v; m0v.x = mu[0]; m0v.y = mu[1]; m0v.z = mu[2]; m0v.w = mu[3];
        uint4 m1v; m1v.x = mu[4]; m1v.y = mu[5]; m1v.z = mu[6]; m1v.w = mu[7];
        *(uint4*)&sB[srow][skh] = m0v;
        *(uint4*)&sB[srow][skh + 8] = m1v;
        __syncthreads();
        short8 af[4], bf[4];
        #pragma unroll
        for (int i = 0; i < 4; ++i) af[i] = *(short8*)&sA[m0w + i * 16 + lr][quad * 8];
        #pragma unroll
        for (int j = 0; j < 4; ++j) bf[j] = *(short8*)&sB[n0w + j * 16 + lr][quad * 8];
        #pragma unroll
        for (int i = 0; i < 4; ++i)
            #pragma unroll
            for (int j = 0; j < 4; ++j)
                acc[i][j] = __builtin_amdgcn_mfma_f32_16x16x32_bf16(af[i], bf[j], acc[i][j], 0, 0, 0);
    }
    #pragma unroll
    for (int i = 0; i < 4; ++i) {
        float4 bs = *(const float4*)&bias[o0 + m0w + i * 16 + quad * 4];
        float bsa[4] = {bs.x, bs.y, bs.z, bs.w};
        #pragma unroll
        for (int j = 0; j < 4; ++j) {
            floatx4 v = acc[i][j];
            int pos = n0 + n0w + j * 16 + lr;
            #pragma unroll
            for (int rg = 0; rg < 4; ++rg) {
                int o = o0 + m0w + i * 16 + quad * 4 + rg;
                float f = v[rg] + bsa[rg];
                float sg = 1.f / (1.f + __expf(-f));
                size_t idx = ((size_t)b * 512 + o) * HW + pos;
                OutF[idx] = X[idx] + sg;
            }
        }
    }
}

// ------------------------------------------------------------------- launcher
extern "C" void kernel_launch(void* const* d_in, const int* in_sizes, int n_in,
                              void* d_out, int out_size, void* d_ws, size_t ws_size,
                              hipStream_t stream) {
    const float* x      = (const float*)d_in[0];
    const float* w_b1   = (const float*)d_in[1];
    const float* b_b1   = (const float*)d_in[2];
    const float* w_b21  = (const float*)d_in[3];
    const float* b_b21  = (const float*)d_in[4];
    const float* w_off2 = (const float*)d_in[5];
    const float* b_off2 = (const float*)d_in[6];
    const float* w_ddc2 = (const float*)d_in[7];
    const float* b_ddc2 = (const float*)d_in[8];
    const float* w_b31  = (const float*)d_in[9];
    const float* b_b31  = (const float*)d_in[10];
    const float* w_off3 = (const float*)d_in[11];
    const float* b_off3 = (const float*)d_in[12];
    const float* w_ddc3 = (const float*)d_in[13];
    const float* b_ddc3 = (const float*)d_in[14];
    const float* w_b4   = (const float*)d_in[15];
    const float* b_b4   = (const float*)d_in[16];
    const float* w_cc   = (const float*)d_in[17];
    const float* b_cc   = (const float*)d_in[18];

    char* wsb = (char*)d_ws;
    unsigned short* ws8  = (unsigned short*)d_ws;
    unsigned short* xbT  = (unsigned short*)(wsb + O_XBT);
    unsigned short* pxb  = (unsigned short*)(wsb + O_PXB);
    unsigned short* catb = (unsigned short*)(wsb + O_CATB);
    unsigned short* wpb  = (unsigned short*)(wsb + O_WPB);
    unsigned short* w4b  = (unsigned short*)(wsb + O_W4B);
    unsigned short* wccb = (unsigned short*)(wsb + O_WCCB);
    unsigned short* wd2t = (unsigned short*)(wsb + O_WD2T);
    unsigned short* wd3t = (unsigned short*)(wsb + O_WD3T);
    unsigned short* wo2t = (unsigned short*)(wsb + O_WO2T);
    unsigned short* wo3t = (unsigned short*)(wsb + O_WO3T);
    unsigned short* t2b  = (unsigned short*)(wsb + O_T2B);
    unsigned short* t3b  = (unsigned short*)(wsb + O_T3B);
    float* off2 = (float*)(wsb + O_OFF2);
    float* off3 = (float*)(wsb + O_OFF3);
    float* out  = (float*)d_out;

    k_prepw<<<dim3(5312), dim3(256), 0, stream>>>(
        w_b1, w_b21, w_b31, w_b4, w_cc, w_ddc2, w_ddc3, w_off2, w_off3, ws8);
    k_xpose<<<dim3(128, 16, 8), dim3(256), 0, stream>>>(x, xbT);
    k_pool<<<dim3(8192), dim3(256), 0, stream>>>(xbT, pxb);
    // b4 first (frees pxb region for t2b/t3b/offsets)
    k_gemm<<<dim3(32, 1, 8), dim3(256), 0, stream>>>(w4b, b_b4, pxb, catb, 512, 384);
    k_gemm<<<dim3(32, 1, 8), dim3(256), 0, stream>>>(wpb, b_b1, xbT, catb, 512, 0);
    k_gemm<<<dim3(32, 1, 8), dim3(256), 0, stream>>>(wpb + 128 * 512, b_b21, xbT, t2b, 128, 0);
    k_gemm<<<dim3(32, 1, 8), dim3(256), 0, stream>>>(wpb + 256 * 512, b_b31, xbT, t3b, 128, 0);
    k_offconv2<3, 18><<<dim3(32, 1, 8), dim3(512), 0, stream>>>(t2b, wo2t, b_off2, off2);
    k_offconv2<5, 50><<<dim3(32, 1, 8), dim3(512), 0, stream>>>(t3b, wo3t, b_off3, off3);
    k_deform11<3><<<dim3(128, 1, 8), dim3(256), 0, stream>>>(t2b, off2, wd2t, b_ddc2, catb, 128);
    k_deform11<5><<<dim3(128, 1, 8), dim3(256), 0, stream>>>(t3b, off3, wd3t, b_ddc3, catb, 256);
    k_gemm_final<<<dim3(32, 4, 8), dim3(256), 0, stream>>>(wccb, b_cc, catb, xbT, x, out);
}

// Round 10
// 527.531 us; speedup vs baseline: 1.0399x; 1.0399x over previous
//
#include <hip/hip_runtime.h>
#include <math.h>

#define HW 4096
typedef short short8 __attribute__((ext_vector_type(8)));
typedef float floatx4 __attribute__((ext_vector_type(4)));

// ---- ws layout (bytes) ----
#define O_XBT   0ull            // [8][4096][512] bf16 x NHWC
#define O_PXB   33554432ull     // [8][4096][512] bf16 pooled x NHWC (reused later)
#define O_CATB  67108864ull     // [8][4096][512] bf16 cat branches NHWC
#define O_WPB   100663296ull    // [384][512] bf16
#define O_W4B   101056512ull    // [128][512] bf16
#define O_WCCB  101187584ull    // [512][512] bf16
#define O_WD2T  101711872ull    // [9][128][128] bf16 (t,o,c)
#define O_WD3T  102006784ull    // [25][128][128] bf16 (t,o,c)
#define O_WO2T  102825984ull    // [9][64][128] bf16 (t,o,c)
#define O_WO3T  102973440ull    // [25][64][128] bf16 (t,o,c)
// reuse of PXB region after b4 GEMM:
#define O_T2B   33554432ull     // [8][4096][128] bf16 b2i NHWC
#define O_T3B   41943040ull     // [8][4096][128] bf16 b3i NHWC
#define O_OFF2  50331648ull     // [8][18][4096] f32
#define O_OFF3  52690944ull     // [8][50][4096] f32

__device__ __forceinline__ unsigned short f2b(float f) {
    union { float f; unsigned u; } v; v.f = f;
    unsigned r = v.u + 0x7FFFu + ((v.u >> 16) & 1u);
    return (unsigned short)(r >> 16);
}
__device__ __forceinline__ float lou(unsigned u) {
    union { unsigned u; float f; } v; v.u = u << 16; return v.f;
}
__device__ __forceinline__ float hiu(unsigned u) {
    union { unsigned u; float f; } v; v.u = u & 0xFFFF0000u; return v.f;
}
__device__ __forceinline__ unsigned pk2(float lo, float hi) {
    return (unsigned)f2b(lo) | ((unsigned)f2b(hi) << 16);
}

// ------------------------------------------------------------- weight prep
__global__ __launch_bounds__(256) void k_prepw(
        const float* __restrict__ w1, const float* __restrict__ w21,
        const float* __restrict__ w31, const float* __restrict__ w4,
        const float* __restrict__ wcc, const float* __restrict__ wd2,
        const float* __restrict__ wd3, const float* __restrict__ wo2,
        const float* __restrict__ wo3, unsigned short* __restrict__ ws8) {
    unsigned i = blockIdx.x * 256 + threadIdx.x;
    unsigned short* wpb  = ws8 + (O_WPB  >> 1);
    unsigned short* w4b  = ws8 + (O_W4B  >> 1);
    unsigned short* wccb = ws8 + (O_WCCB >> 1);
    unsigned short* wd2t = ws8 + (O_WD2T >> 1);
    unsigned short* wd3t = ws8 + (O_WD3T >> 1);
    unsigned short* wo2t = ws8 + (O_WO2T >> 1);
    unsigned short* wo3t = ws8 + (O_WO3T >> 1);
    if (i < 196608) {
        int o = i >> 9;
        float v = (o < 128) ? w1[i] : (o < 256) ? w21[i - 65536] : w31[i - 131072];
        wpb[i] = f2b(v);
    } else if (i < 262144) {
        unsigned j = i - 196608; w4b[j] = f2b(w4[j]);
    } else if (i < 524288) {
        unsigned j = i - 262144; wccb[j] = f2b(wcc[j]);
    } else if (i < 671744) {
        unsigned j = i - 524288; int t = j >> 14, o = (j >> 7) & 127, c = j & 127;
        wd2t[j] = f2b(wd2[((o * 128 + c) * 9) + t]);
    } else if (i < 1081344) {
        unsigned j = i - 671744; int t = j >> 14, o = (j >> 7) & 127, c = j & 127;
        wd3t[j] = f2b(wd3[((o * 128 + c) * 25) + t]);
    } else if (i < 1155072) {
        // layout (t, o, c): j = (t*64 + o)*128 + c
        unsigned j = i - 1081344; int t = j >> 13, o = (j >> 7) & 63, c = j & 127;
        wo2t[j] = (o < 18) ? f2b(wo2[((o * 128 + c) * 9) + t]) : 0;
    } else if (i < 1359872) {
        unsigned j = i - 1155072; int t = j >> 13, o = (j >> 7) & 63, c = j & 127;
        wo3t[j] = (o < 50) ? f2b(wo3[((o * 128 + c) * 25) + t]) : 0;
    }
}

// ---------------------------------------- x NCHW f32 -> NHWC bf16 transpose
__global__ __launch_bounds__(256) void k_xpose(const float* __restrict__ X,
                                               unsigned short* __restrict__ xbT) {
    __shared__ unsigned short t[32][33];
    const int p0 = blockIdx.x * 32, c0 = blockIdx.y * 32, b = blockIdx.z;
    const int tid = threadIdx.x;
    #pragma unroll
    for (int s = 0; s < 4; ++s) {
        int cl = s * 8 + (tid >> 5), pl = tid & 31;
        t[cl][pl] = f2b(X[((size_t)b * 512 + c0 + cl) * HW + p0 + pl]);
    }
    __syncthreads();
    #pragma unroll
    for (int s = 0; s < 4; ++s) {
        int pl = s * 8 + (tid >> 5), cl = tid & 31;
        xbT[((size_t)b * HW + p0 + pl) * 512 + c0 + cl] = t[cl][pl];
    }
}

// ----------------------------------------------- 3x3 s1 maxpool on NHWC bf16
__global__ __launch_bounds__(256) void k_pool(const unsigned short* __restrict__ xbT,
                                              unsigned short* __restrict__ pxb) {
    unsigned gid = blockIdx.x * 256 + threadIdx.x;   // 8*4096*64
    int b = gid >> 18;
    unsigned rem = gid & 262143;
    int pos = rem >> 6;
    int cg = (rem & 63) * 8;
    int h = pos >> 6, w = pos & 63;
    const unsigned short* img = xbT + (size_t)b * HW * 512;
    float m[8] = {-INFINITY, -INFINITY, -INFINITY, -INFINITY,
                  -INFINITY, -INFINITY, -INFINITY, -INFINITY};
    #pragma unroll
    for (int dy = -1; dy <= 1; ++dy) {
        int hh = h + dy;
        if (hh < 0 || hh >= 64) continue;
        #pragma unroll
        for (int dx = -1; dx <= 1; ++dx) {
            int ww = w + dx;
            if (ww < 0 || ww >= 64) continue;
            uint4 v = *(const uint4*)(img + ((size_t)(hh * 64 + ww)) * 512 + cg);
            unsigned uu[4] = {v.x, v.y, v.z, v.w};
            #pragma unroll
            for (int e = 0; e < 4; ++e) {
                m[2 * e]     = fmaxf(m[2 * e],     lou(uu[e]));
                m[2 * e + 1] = fmaxf(m[2 * e + 1], hiu(uu[e]));
            }
        }
    }
    uint4 o;
    o.x = pk2(m[0], m[1]); o.y = pk2(m[2], m[3]);
    o.z = pk2(m[4], m[5]); o.w = pk2(m[6], m[7]);
    *(uint4*)(pxb + ((size_t)b * HW + pos) * 512 + cg) = o;
}

// ----------------------------- bf16 MFMA GEMM: C[128 x 128pos] = A[128x512]B
#define SA(r,c) SM[(r)*40 + (c)]
#define SB(r,c) SM[5120 + (r)*40 + (c)]
#define SC(r,c) SM[(r)*136 + (c)]
__global__ __launch_bounds__(256) void k_gemm(
        const unsigned short* __restrict__ A, const float* __restrict__ bias,
        const unsigned short* __restrict__ Bm,
        unsigned short* __restrict__ dst, int dStride, int dOff) {
    __shared__ unsigned short SM[17408];
    const int tid = threadIdx.x;
    const int n0 = blockIdx.x * 128;
    const int b = blockIdx.z;
    const int wave = tid >> 6, lane = tid & 63, quad = lane >> 4, lr = lane & 15;
    const int m0w = (wave & 1) * 64, n0w = (wave >> 1) * 64;
    const int srow = tid >> 1, skh = (tid & 1) * 16;
    floatx4 acc[4][4] = {};

    for (int k0 = 0; k0 < 512; k0 += 32) {
        const unsigned short* ga = A + (size_t)srow * 512 + k0 + skh;
        uint4 a0 = *(const uint4*)(ga);
        uint4 a1 = *(const uint4*)(ga + 8);
        const unsigned short* gb = Bm + ((size_t)b * HW + n0 + srow) * 512 + k0 + skh;
        uint4 b0 = *(const uint4*)(gb);
        uint4 b1 = *(const uint4*)(gb + 8);
        __syncthreads();
        *(uint4*)&SA(srow, skh) = a0;
        *(uint4*)&SA(srow, skh + 8) = a1;
        *(uint4*)&SB(srow, skh) = b0;
        *(uint4*)&SB(srow, skh + 8) = b1;
        __syncthreads();
        short8 af[4], bf[4];
        #pragma unroll
        for (int i = 0; i < 4; ++i) af[i] = *(short8*)&SA(m0w + i * 16 + lr, quad * 8);
        #pragma unroll
        for (int j = 0; j < 4; ++j) bf[j] = *(short8*)&SB(n0w + j * 16 + lr, quad * 8);
        #pragma unroll
        for (int i = 0; i < 4; ++i)
            #pragma unroll
            for (int j = 0; j < 4; ++j)
                acc[i][j] = __builtin_amdgcn_mfma_f32_16x16x32_bf16(af[i], bf[j], acc[i][j], 0, 0, 0);
    }
    __syncthreads();
    #pragma unroll
    for (int i = 0; i < 4; ++i) {
        float4 bs = *(const float4*)&bias[m0w + i * 16 + quad * 4];
        #pragma unroll
        for (int j = 0; j < 4; ++j) {
            floatx4 v = acc[i][j];
            int pos = n0w + j * 16 + lr;
            int ch = m0w + i * 16 + quad * 4;
            uint2 st;
            st.x = pk2(v[0] + bs.x, v[1] + bs.y);
            st.y = pk2(v[2] + bs.z, v[3] + bs.w);
            *(uint2*)&SC(pos, ch) = st;
        }
    }
    __syncthreads();
    #pragma unroll
    for (int r = 0; r < 8; ++r) {
        int pos = (tid >> 4) + r * 16;
        *(uint4*)&dst[((size_t)b * HW + n0 + pos) * dStride + dOff + (tid & 15) * 8] =
            *(uint4*)&SC(pos, (tid & 15) * 8);
    }
}

// -------- fused 3-branch GEMM: b1/b21/b31 share xbT; blockIdx.y selects
// branch. 768 blocks = 3/CU -> inter-block overlap the separate launches
// (256 blocks = 1/CU each) could never have.
__global__ __launch_bounds__(256) void k_gemm3(
        const unsigned short* __restrict__ Wpb, const float* __restrict__ bs1,
        const float* __restrict__ bs21, const float* __restrict__ bs31,
        const unsigned short* __restrict__ xbT,
        unsigned short* __restrict__ catb, unsigned short* __restrict__ t2b,
        unsigned short* __restrict__ t3b) {
    __shared__ unsigned short SM[17408];
    const int tid = threadIdx.x;
    const int n0 = blockIdx.x * 128;
    const int y = blockIdx.y;
    const int b = blockIdx.z;
    const unsigned short* A = Wpb + (size_t)y * 128 * 512;
    const float* bias = (y == 0) ? bs1 : (y == 1) ? bs21 : bs31;
    unsigned short* dst = (y == 0) ? catb : (y == 1) ? t2b : t3b;
    const int dStride = (y == 0) ? 512 : 128;
    const int wave = tid >> 6, lane = tid & 63, quad = lane >> 4, lr = lane & 15;
    const int m0w = (wave & 1) * 64, n0w = (wave >> 1) * 64;
    const int srow = tid >> 1, skh = (tid & 1) * 16;
    floatx4 acc[4][4] = {};

    for (int k0 = 0; k0 < 512; k0 += 32) {
        const unsigned short* ga = A + (size_t)srow * 512 + k0 + skh;
        uint4 a0 = *(const uint4*)(ga);
        uint4 a1 = *(const uint4*)(ga + 8);
        const unsigned short* gb = xbT + ((size_t)b * HW + n0 + srow) * 512 + k0 + skh;
        uint4 b0 = *(const uint4*)(gb);
        uint4 b1 = *(const uint4*)(gb + 8);
        __syncthreads();
        *(uint4*)&SA(srow, skh) = a0;
        *(uint4*)&SA(srow, skh + 8) = a1;
        *(uint4*)&SB(srow, skh) = b0;
        *(uint4*)&SB(srow, skh + 8) = b1;
        __syncthreads();
        short8 af[4], bf[4];
        #pragma unroll
        for (int i = 0; i < 4; ++i) af[i] = *(short8*)&SA(m0w + i * 16 + lr, quad * 8);
        #pragma unroll
        for (int j = 0; j < 4; ++j) bf[j] = *(short8*)&SB(n0w + j * 16 + lr, quad * 8);
        #pragma unroll
        for (int i = 0; i < 4; ++i)
            #pragma unroll
            for (int j = 0; j < 4; ++j)
                acc[i][j] = __builtin_amdgcn_mfma_f32_16x16x32_bf16(af[i], bf[j], acc[i][j], 0, 0, 0);
    }
    __syncthreads();
    #pragma unroll
    for (int i = 0; i < 4; ++i) {
        float4 bs = *(const float4*)&bias[m0w + i * 16 + quad * 4];
        #pragma unroll
        for (int j = 0; j < 4; ++j) {
            floatx4 v = acc[i][j];
            int pos = n0w + j * 16 + lr;
            int ch = m0w + i * 16 + quad * 4;
            uint2 st;
            st.x = pk2(v[0] + bs.x, v[1] + bs.y);
            st.y = pk2(v[2] + bs.z, v[3] + bs.w);
            *(uint2*)&SC(pos, ch) = st;
        }
    }
    __syncthreads();
    #pragma unroll
    for (int r = 0; r < 8; ++r) {
        int pos = (tid >> 4) + r * 16;
        *(uint4*)&dst[((size_t)b * HW + n0 + pos) * dStride + (tid & 15) * 8] =
            *(uint4*)&SC(pos, (tid & 15) * 8);
    }
}

// ---------------- offset convs v2: slab-staged, barrier-free tap loop
// block = 128 positions (2 h-rows) x 64 M (padded), 512 threads.
template<int KS, int OCH>
__global__ __launch_bounds__(512) void k_offconv2(
        const unsigned short* __restrict__ img,   // [B][4096][128] bf16
        const unsigned short* __restrict__ woT,   // [TT][64][128] bf16 (t,o,c)
        const float* __restrict__ bias, float* __restrict__ Out) {
    constexpr int PAD = KS / 2;
    constexpr int TT = KS * KS;
    constexpr int SR = 2 + 2 * PAD;
    constexpr int SC2 = 64 + 2 * PAD;
    constexpr int NE = SR * SC2;              // slab entries
    __shared__ unsigned short slab[NE * 36];  // [entry][36] (32 ch + pad)
    __shared__ float ctile[64 * 132];
    const int tid = threadIdx.x;
    const int p0 = blockIdx.x * 128, hrow0 = blockIdx.x * 2, b = blockIdx.z;
    const int wave = tid >> 6, lane = tid & 63, quad = lane >> 4, lr = lane & 15;
    const int wm = wave & 1, wn = wave >> 1;   // 2 x 4 wave grid: 32o x 32pos
    const unsigned short* ib = img + (size_t)b * HW * 128;
    floatx4 acc[2][2] = {};

    for (int c0 = 0; c0 < 128; c0 += 32) {
        __syncthreads();
        if (tid < NE) {
            int s = tid / SC2, cl = tid % SC2;
            int r = hrow0 - PAD + s, cc = cl - PAD;
            uint4 v0 = {}, v1 = {}, v2 = {}, v3 = {};
            if ((unsigned)r < 64u && (unsigned)cc < 64u) {
                const uint4* g = (const uint4*)(ib + ((size_t)(r * 64 + cc)) * 128 + c0);
                v0 = g[0]; v1 = g[1]; v2 = g[2]; v3 = g[3];
            }
            uint2* d2 = (uint2*)&slab[tid * 36];
            d2[0] = make_uint2(v0.x, v0.y); d2[1] = make_uint2(v0.z, v0.w);
            d2[2] = make_uint2(v1.x, v1.y); d2[3] = make_uint2(v1.z, v1.w);
            d2[4] = make_uint2(v2.x, v2.y); d2[5] = make_uint2(v2.z, v2.w);
            d2[6] = make_uint2(v3.x, v3.y); d2[7] = make_uint2(v3.z, v3.w);
        }
        __syncthreads();
        #pragma unroll
        for (int t = 0; t < TT; ++t) {
            const int ky = t / KS, kx = t % KS;
            short8 af[2], bf[2];
            #pragma unroll
            for (int i = 0; i < 2; ++i)
                af[i] = *(const short8*)&woT[((size_t)t * 64 + wm * 32 + i * 16 + lr) * 128
                                             + c0 + quad * 8];
            #pragma unroll
            for (int j = 0; j < 2; ++j) {
                int p = wn * 32 + j * 16 + lr;
                int e = ((p >> 6) + ky) * SC2 + (p & 63) + kx;
                union { uint2 u[2]; short8 s; } bb;
                const uint2* sp = (const uint2*)&slab[e * 36 + quad * 8];
                bb.u[0] = sp[0]; bb.u[1] = sp[1];
                bf[j] = bb.s;
            }
            #pragma unroll
            for (int i = 0; i < 2; ++i)
                #pragma unroll
                for (int j = 0; j < 2; ++j)
                    acc[i][j] = __builtin_amdgcn_mfma_f32_16x16x32_bf16(af[i], bf[j], acc[i][j], 0, 0, 0);
        }
    }
    __syncthreads();
    #pragma unroll
    for (int i = 0; i < 2; ++i)
        #pragma unroll
        for (int j = 0; j < 2; ++j) {
            floatx4 v = acc[i][j];
            int p = wn * 32 + j * 16 + lr;
            int o = wm * 32 + i * 16 + quad * 4;
            #pragma unroll
            for (int rg = 0; rg < 4; ++rg)
                ctile[(o + rg) * 132 + p] = v[rg];
        }
    __syncthreads();
    {
        int o = tid >> 3, seg = tid & 7;
        if (o < OCH) {
            float bs = bias[o];
            const float* src = &ctile[o * 132 + seg * 16];
            float* dst = &Out[((size_t)b * OCH + o) * HW + p0 + seg * 16];
            #pragma unroll
            for (int q = 0; q < 4; ++q) {
                float4 v = *(const float4*)(src + q * 4);
                v.x += bs; v.y += bs; v.z += bs; v.w += bs;
                *(float4*)(dst + q * 4) = v;
            }
        }
    }
}

// ------------- deformable conv v10 (PROVEN 129.7us): 4-wave blocks, 4/CU
// block = 256 threads (4 waves), tile = 128 o x 32 pos, grid = (128,1,8).
// XCD-pinned batch (x&7): FETCH 49.5->10.6MB proven (R4).
#define DC_GATHER(T, DY, DX) do {                                              \
    float fy = (float)(h + (T) / KS - PAD) + (DY);                             \
    float fx = (float)(w + (T) % KS - PAD) + (DX);                             \
    float y0f = floorf(fy), x0f = floorf(fx);                                  \
    float wyv = fy - y0f, wxv = fx - x0f;                                      \
    int y0 = (int)y0f, x0 = (int)x0f;                                          \
    w00 = (1.f - wyv) * (1.f - wxv); w01 = (1.f - wyv) * wxv;                  \
    w10 = wyv * (1.f - wxv);         w11 = wyv * wxv;                          \
    bool yv0 = (unsigned)y0 < 64u, yv1 = (unsigned)(y0 + 1) < 64u;             \
    bool xv0 = (unsigned)x0 < 64u, xv1 = (unsigned)(x0 + 1) < 64u;             \
    long bidx = (long)(y0 * 64 + x0) * 128 + cseg;                             \
    cn0 = z4; cn1 = z4; cn2 = z4; cn3 = z4;                                    \
    cn4 = z4; cn5 = z4; cn6 = z4; cn7 = z4;                                    \
    if (yv0 && xv0) { const uint4* p_ = (const uint4*)(ib + bidx);             \
        cn0 = p_[0]; cn1 = p_[1]; }                                            \
    if (yv0 && xv1) { const uint4* p_ = (const uint4*)(ib + bidx + 128);       \
        cn2 = p_[0]; cn3 = p_[1]; }                                            \
    if (yv1 && xv0) { const uint4* p_ = (const uint4*)(ib + bidx + 8192);      \
        cn4 = p_[0]; cn5 = p_[1]; }                                            \
    if (yv1 && xv1) { const uint4* p_ = (const uint4*)(ib + bidx + 8320);      \
        cn6 = p_[0]; cn7 = p_[1]; }                                            \
} while (0)

// blend with v_cvt_pk_bf16_f32 (RNE, bit-identical to f2b emulation)
#define DC_BLEND(RA, RB, RC, RD, OUT) do {                                     \
    unsigned a_[4] = {RA.x, RA.y, RA.z, RA.w};                                 \
    unsigned b_[4] = {RB.x, RB.y, RB.z, RB.w};                                 \
    unsigned c_[4] = {RC.x, RC.y, RC.z, RC.w};                                 \
    unsigned d_[4] = {RD.x, RD.y, RD.z, RD.w};                                 \
    unsigned r_[4];                                                            \
    _Pragma("unroll")                                                          \
    for (int e_ = 0; e_ < 4; ++e_) {                                           \
        float lo_ = w00 * lou(a_[e_]) + w01 * lou(b_[e_])                      \
                  + w10 * lou(c_[e_]) + w11 * lou(d_[e_]);                     \
        float hi_ = w00 * hiu(a_[e_]) + w01 * hiu(b_[e_])                      \
                  + w10 * hiu(c_[e_]) + w11 * hiu(d_[e_]);                     \
        asm("v_cvt_pk_bf16_f32 %0, %1, %2"                                     \
            : "=v"(r_[e_]) : "v"(lo_), "v"(hi_));                              \
    }                                                                          \
    OUT.x = r_[0]; OUT.y = r_[1]; OUT.z = r_[2]; OUT.w = r_[3];                \
} while (0)

template<int KS>
__global__ __launch_bounds__(256, 4) void k_deform10(
        const unsigned short* __restrict__ img,   // [B][4096][128] bf16
        const float* __restrict__ Off,            // [B][2TT][4096] f32
        const unsigned short* __restrict__ wdT,   // [TT][128][128] bf16 (t,o,c)
        const float* __restrict__ bias,
        unsigned short* __restrict__ catb, int dOff) {
    constexpr int PAD = KS / 2;
    constexpr int TT = KS * KS;
    __shared__ unsigned short sS[2][32][136];  // samples [buf][pos][c], +8 pad
    const int tid = threadIdx.x;
    // XCD-pinned remap: all blocks of batch b land on XCD b (L%8 model)
    const int b = blockIdx.x & 7;
    const int tile = (blockIdx.x >> 3) + 16 * blockIdx.z;  // 0..127
    const int p0 = tile * 32;
    const int wave = tid >> 6, lane = tid & 63, quad = lane >> 4, lr = lane & 15;
    const int m0w = wave * 32;                 // 4 m-waves x 32 o, all share 32 pos
    const int pos = tid >> 3;                  // 0..31
    const int cseg = (tid & 7) * 16;           // 16-ch segment
    const int pglob = p0 + pos;
    const int h = pglob >> 6, w = pglob & 63;
    const unsigned short* ib = img + (size_t)b * HW * 128;
    const float* offb = Off + (size_t)b * 2 * TT * HW;
    const uint4 z4 = make_uint4(0u, 0u, 0u, 0u);

    floatx4 acc00 = {}, acc01 = {}, acc10 = {}, acc11 = {};
    uint4 cn0, cn1, cn2, cn3, cn4, cn5, cn6, cn7;   // corners (A,B,C,D)x2
    float w00, w01, w10, w11;
    float noy = 0.f, nox = 0.f;

    // prologue: gather tap 0; prefetch offsets for tap 1
    {
        float dy0 = offb[pglob];
        float dx0 = offb[HW + pglob];
        DC_GATHER(0, dy0, dx0);
    }
    if (TT > 1) { noy = offb[2 * HW + pglob]; nox = offb[3 * HW + pglob]; }

    for (int t = 0; t < TT; ++t) {
        const int cur = t & 1;
        // INTERP(t): blend corners -> 16 bf16 samples
        uint4 ov0, ov1;
        DC_BLEND(cn0, cn2, cn4, cn6, ov0);
        DC_BLEND(cn1, cn3, cn5, cn7, ov1);
        *(uint4*)&sS[cur][pos][cseg] = ov0;
        *(uint4*)&sS[cur][pos][cseg + 8] = ov1;
        // weights(t) -> named regs, issued BEFORE the barrier so their L2
        // latency overlaps the barrier rendezvous
        const unsigned short* wb = wdT + (size_t)t * 16384
                                   + (size_t)(m0w + lr) * 128 + quad * 8;
        short8 wr0 = *(const short8*)(wb);
        short8 wr1 = *(const short8*)(wb + 2048);        // row +16
        short8 wr2 = *(const short8*)(wb + 32);          // ks=1
        short8 wr3 = *(const short8*)(wb + 2080);
        short8 wr4 = *(const short8*)(wb + 64);          // ks=2
        short8 wr5 = *(const short8*)(wb + 2112);
        short8 wr6 = *(const short8*)(wb + 96);          // ks=3
        short8 wr7 = *(const short8*)(wb + 2144);
        __syncthreads();
        // issue gathers(t+1), prefetch offsets(t+2) — in flight through MFMA(t)
        if (t + 1 < TT) {
            DC_GATHER(t + 1, noy, nox);
            if (t + 2 < TT) {
                noy = offb[(size_t)(2 * t + 4) * HW + pglob];
                nox = offb[(size_t)(2 * t + 5) * HW + pglob];
            }
        }
        // MFMA(t): 128o x 32pos per block, 32o rows per wave
        #pragma unroll
        for (int ks = 0; ks < 4; ++ks) {
            short8 bf0 = *(short8*)&sS[cur][lr][ks * 32 + quad * 8];
            short8 bf1 = *(short8*)&sS[cur][16 + lr][ks * 32 + quad * 8];
            short8 a0 = (ks == 0) ? wr0 : (ks == 1) ? wr2 : (ks == 2) ? wr4 : wr6;
            short8 a1 = (ks == 0) ? wr1 : (ks == 1) ? wr3 : (ks == 2) ? wr5 : wr7;
            acc00 = __builtin_amdgcn_mfma_f32_16x16x32_bf16(a0, bf0, acc00, 0, 0, 0);
            acc01 = __builtin_amdgcn_mfma_f32_16x16x32_bf16(a0, bf1, acc01, 0, 0, 0);
            acc10 = __builtin_amdgcn_mfma_f32_16x16x32_bf16(a1, bf0, acc10, 0, 0, 0);
            acc11 = __builtin_amdgcn_mfma_f32_16x16x32_bf16(a1, bf1, acc11, 0, 0, 0);
        }
    }
    // epilogue: bias + bf16 pack via sS[0], coalesced store to catb
    __syncthreads();
    {
        float4 bs = *(const float4*)&bias[m0w + quad * 4];
        float4 bs2 = *(const float4*)&bias[m0w + 16 + quad * 4];
        floatx4 v;
        uint2 st;
        int ch0 = m0w + quad * 4, ch1 = m0w + 16 + quad * 4;
        v = acc00;
        st.x = pk2(v[0] + bs.x, v[1] + bs.y);
        st.y = pk2(v[2] + bs.z, v[3] + bs.w);
        *(uint2*)&sS[0][lr][ch0] = st;
        v = acc01;
        st.x = pk2(v[0] + bs.x, v[1] + bs.y);
        st.y = pk2(v[2] + bs.z, v[3] + bs.w);
        *(uint2*)&sS[0][16 + lr][ch0] = st;
        v = acc10;
        st.x = pk2(v[0] + bs2.x, v[1] + bs2.y);
        st.y = pk2(v[2] + bs2.z, v[3] + bs2.w);
        *(uint2*)&sS[0][lr][ch1] = st;
        v = acc11;
        st.x = pk2(v[0] + bs2.x, v[1] + bs2.y);
        st.y = pk2(v[2] + bs2.z, v[3] + bs2.w);
        *(uint2*)&sS[0][16 + lr][ch1] = st;
    }
    __syncthreads();
    #pragma unroll
    for (int r = 0; r < 2; ++r) {
        int idx = r * 256 + tid;
        int p = idx >> 4, sg = (idx & 15) * 8;
        *(uint4*)&catb[((size_t)b * HW + p0 + p) * 512 + dOff + sg] =
            *(uint4*)&sS[0][p][sg];
    }
}

// ------------------- final: sigmoid(Wcc @ (catb*xbT)) + x, fp32 NCHW output
__global__ __launch_bounds__(256) void k_gemm_final(
        const unsigned short* __restrict__ A, const float* __restrict__ bias,
        const unsigned short* __restrict__ catb, const unsigned short* __restrict__ xbT,
        const float* __restrict__ X, float* __restrict__ OutF) {
    __shared__ unsigned short sA[128][40];
    __shared__ unsigned short sB[128][40];
    const int tid = threadIdx.x;
    const int n0 = blockIdx.x * 128;
    const int o0 = blockIdx.y * 128;
    const int b = blockIdx.z;
    const int wave = tid >> 6, lane = tid & 63, quad = lane >> 4, lr = lane & 15;
    const int m0w = (wave & 1) * 64, n0w = (wave >> 1) * 64;
    const int srow = tid >> 1, skh = (tid & 1) * 16;
    floatx4 acc[4][4] = {};

    for (int k0 = 0; k0 < 512; k0 += 32) {
        const unsigned short* ga = A + (size_t)(o0 + srow) * 512 + k0 + skh;
        uint4 a0 = *(const uint4*)(ga);
        uint4 a1 = *(const uint4*)(ga + 8);
        size_t bi = ((size_t)b * HW + n0 + srow) * 512 + k0 + skh;
        uint4 c0 = *(const uint4*)(catb + bi);
        uint4 c1 = *(const uint4*)(catb + bi + 8);
        uint4 x0 = *(const uint4*)(xbT + bi);
        uint4 x1 = *(const uint4*)(xbT + bi + 8);
        unsigned cu[8] = {c0.x, c0.y, c0.z, c0.w, c1.x, c1.y, c1.z, c1.w};
        unsigned xu[8] = {x0.x, x0.y, x0.z, x0.w, x1.x, x1.y, x1.z, x1.w};
        unsigned mu[8];
        #pragma unroll
        for (int e = 0; e < 8; ++e)
            mu[e] = pk2(lou(cu[e]) * lou(xu[e]), hiu(cu[e]) * hiu(xu[e]));
        __syncthreads();
        *(uint4*)&sA[srow][skh] = a0;
        *(uint4*)&sA[srow][skh + 8] = a1;
        uint4 m0v; m0v.x = mu[0]; m0v.y = mu[1]; m0v.z = mu[2]; m0v.w = mu[3];
        uint4 m1v; m1v.x = mu[4]; m1v.y = mu[5]; m1v.z = mu[6]; m1v.w = mu[7];
        *(uint4*)&sB[srow][skh] = m0v;
        *(uint4*)&sB[srow][skh + 8] = m1v;
        __syncthreads();
        short8 af[4], bf[4];
        #pragma unroll
        for (int i = 0; i < 4; ++i) af[i] = *(short8*)&sA[m0w + i * 16 + lr][quad * 8];
        #pragma unroll
        for (int j = 0; j < 4; ++j) bf[j] = *(short8*)&sB[n0w + j * 16 + lr][quad * 8];
        #pragma unroll
        for (int i = 0; i < 4; ++i)
            #pragma unroll
            for (int j = 0; j < 4; ++j)
                acc[i][j] = __builtin_amdgcn_mfma_f32_16x16x32_bf16(af[i], bf[j], acc[i][j], 0, 0, 0);
    }
    #pragma unroll
    for (int i = 0; i < 4; ++i) {
        float4 bs = *(const float4*)&bias[o0 + m0w + i * 16 + quad * 4];
        float bsa[4] = {bs.x, bs.y, bs.z, bs.w};
        #pragma unroll
        for (int j = 0; j < 4; ++j) {
            floatx4 v = acc[i][j];
            int pos = n0 + n0w + j * 16 + lr;
            #pragma unroll
            for (int rg = 0; rg < 4; ++rg) {
                int o = o0 + m0w + i * 16 + quad * 4 + rg;
                float f = v[rg] + bsa[rg];
                float sg = 1.f / (1.f + __expf(-f));
                size_t idx = ((size_t)b * 512 + o) * HW + pos;
                OutF[idx] = X[idx] + sg;
            }
        }
    }
}

// ------------------------------------------------------------------- launcher
extern "C" void kernel_launch(void* const* d_in, const int* in_sizes, int n_in,
                              void* d_out, int out_size, void* d_ws, size_t ws_size,
                              hipStream_t stream) {
    const float* x      = (const float*)d_in[0];
    const float* w_b1   = (const float*)d_in[1];
    const float* b_b1   = (const float*)d_in[2];
    const float* w_b21  = (const float*)d_in[3];
    const float* b_b21  = (const float*)d_in[4];
    const float* w_off2 = (const float*)d_in[5];
    const float* b_off2 = (const float*)d_in[6];
    const float* w_ddc2 = (const float*)d_in[7];
    const float* b_ddc2 = (const float*)d_in[8];
    const float* w_b31  = (const float*)d_in[9];
    const float* b_b31  = (const float*)d_in[10];
    const float* w_off3 = (const float*)d_in[11];
    const float* b_off3 = (const float*)d_in[12];
    const float* w_ddc3 = (const float*)d_in[13];
    const float* b_ddc3 = (const float*)d_in[14];
    const float* w_b4   = (const float*)d_in[15];
    const float* b_b4   = (const float*)d_in[16];
    const float* w_cc   = (const float*)d_in[17];
    const float* b_cc   = (const float*)d_in[18];

    char* wsb = (char*)d_ws;
    unsigned short* ws8  = (unsigned short*)d_ws;
    unsigned short* xbT  = (unsigned short*)(wsb + O_XBT);
    unsigned short* pxb  = (unsigned short*)(wsb + O_PXB);
    unsigned short* catb = (unsigned short*)(wsb + O_CATB);
    unsigned short* wpb  = (unsigned short*)(wsb + O_WPB);
    unsigned short* w4b  = (unsigned short*)(wsb + O_W4B);
    unsigned short* wccb = (unsigned short*)(wsb + O_WCCB);
    unsigned short* wd2t = (unsigned short*)(wsb + O_WD2T);
    unsigned short* wd3t = (unsigned short*)(wsb + O_WD3T);
    unsigned short* wo2t = (unsigned short*)(wsb + O_WO2T);
    unsigned short* wo3t = (unsigned short*)(wsb + O_WO3T);
    unsigned short* t2b  = (unsigned short*)(wsb + O_T2B);
    unsigned short* t3b  = (unsigned short*)(wsb + O_T3B);
    float* off2 = (float*)(wsb + O_OFF2);
    float* off3 = (float*)(wsb + O_OFF3);
    float* out  = (float*)d_out;

    k_prepw<<<dim3(5312), dim3(256), 0, stream>>>(
        w_b1, w_b21, w_b31, w_b4, w_cc, w_ddc2, w_ddc3, w_off2, w_off3, ws8);
    k_xpose<<<dim3(128, 16, 8), dim3(256), 0, stream>>>(x, xbT);
    k_pool<<<dim3(8192), dim3(256), 0, stream>>>(xbT, pxb);
    // b4 first (frees pxb region for t2b/t3b/offsets)
    k_gemm<<<dim3(32, 1, 8), dim3(256), 0, stream>>>(w4b, b_b4, pxb, catb, 512, 384);
    // fused b1/b21/b31 (share xbT): 768 blocks = 3/CU
    k_gemm3<<<dim3(32, 3, 8), dim3(256), 0, stream>>>(
        wpb, b_b1, b_b21, b_b31, xbT, catb, t2b, t3b);
    k_offconv2<3, 18><<<dim3(32, 1, 8), dim3(512), 0, stream>>>(t2b, wo2t, b_off2, off2);
    k_offconv2<5, 50><<<dim3(32, 1, 8), dim3(512), 0, stream>>>(t3b, wo3t, b_off3, off3);
    k_deform10<3><<<dim3(128, 1, 8), dim3(256), 0, stream>>>(t2b, off2, wd2t, b_ddc2, catb, 128);
    k_deform10<5><<<dim3(128, 1, 8), dim3(256), 0, stream>>>(t3b, off3, wd3t, b_ddc3, catb, 256);
    k_gemm_final<<<dim3(32, 4, 8), dim3(256), 0, stream>>>(wccb, b_cc, catb, xbT, x, out);
}